// Round 1
// baseline (376.048 us; speedup 1.0000x reference)
//
#include <hip/hip_runtime.h>
#include <hip/hip_bf16.h>

// GIN: 3x fused [CSR gather-sum + MLP(64->64->64) + relu] + mean-pool(128) + linear(64->10)
// gmlp: gather fused into MLP. Each block = one 64-row tile; each wave gathers its
//   16 rows (dual 8-deep load pipelines, fabric-BW-bound ~3 TB/s) into LDS hs, then
//   GEMM1->GEMM2->(pool) from LDS. Removes h round-trip (77 MB/iter) + 3 launches.
// CSR: 391-bucket binning + per-bucket counting sort w/ inline prefix (no bscan).
// tobf zeroes bcnt+gsum (no memsets). 7 dispatches total.

#define N_NODES 100000
#define N_EDGES 1200000
#define N_GRAPH 128
#define N_CLS   10
#define NBUCK   391        // dst >> 8
#define BCAP    4096       // per-bucket capacity (mean 3070, +18 sigma)
#define BSH     12         // log2(BCAP)

typedef __bf16 bf16_t;
typedef __bf16 bf16x8 __attribute__((ext_vector_type(8)));
typedef float  f32x4  __attribute__((ext_vector_type(4)));

// ---------------- x -> bf16 (+ zero bcnt/gsum for later kernels) ----------------
__global__ void tobf_kernel(const float* __restrict__ x, bf16_t* __restrict__ xb,
                            int* __restrict__ bcnt, float* __restrict__ gsum) {
    if (blockIdx.x == 0) {
        for (int i = threadIdx.x; i < NBUCK; i += 256) bcnt[i] = 0;
    } else if (blockIdx.x == 1) {
        f32x4* g4 = (f32x4*)gsum;
        for (int i = threadIdx.x; i < N_GRAPH * 16; i += 256)   // 8192 f32
            g4[i] = (f32x4){0.f, 0.f, 0.f, 0.f};
    }
    const int i = (blockIdx.x * 256 + threadIdx.x) * 8;
    const f32x4 a = *(const f32x4*)(x + i);
    const f32x4 b = *(const f32x4*)(x + i + 4);
    bf16x8 o;
#pragma unroll
    for (int j = 0; j < 4; ++j) { o[j] = (bf16_t)a[j]; o[4 + j] = (bf16_t)b[j]; }
    *(bf16x8*)(xb + i) = o;
}

// ---------------- CSR build ----------------
__global__ void binA_kernel(const int* __restrict__ ei,
                            int* __restrict__ bcnt,
                            int* __restrict__ bpair) {
    __shared__ int lcnt[NBUCK];
    __shared__ int lbase[NBUCK];
    const int t = threadIdx.x;
    for (int b = t; b < NBUCK; b += 256) lcnt[b] = 0;
    __syncthreads();
    const int e0 = (blockIdx.x * 256 + t) * 4;
    int4 s4, d4; int b[4], r[4];
    const bool valid = e0 < N_EDGES;               // N_EDGES % 4 == 0
    if (valid) {
        s4 = *(const int4*)(ei + e0);
        d4 = *(const int4*)(ei + N_EDGES + e0);
        b[0] = d4.x >> 8; b[1] = d4.y >> 8; b[2] = d4.z >> 8; b[3] = d4.w >> 8;
        r[0] = atomicAdd(&lcnt[b[0]], 1);
        r[1] = atomicAdd(&lcnt[b[1]], 1);
        r[2] = atomicAdd(&lcnt[b[2]], 1);
        r[3] = atomicAdd(&lcnt[b[3]], 1);
    }
    __syncthreads();
    for (int bb = t; bb < NBUCK; bb += 256) {
        const int c = lcnt[bb];
        lbase[bb] = c ? atomicAdd(&bcnt[bb], c) : 0;
    }
    __syncthreads();
    if (valid) {
        const int ss[4] = {s4.x, s4.y, s4.z, s4.w};
        const int dd[4] = {d4.x, d4.y, d4.z, d4.w};
#pragma unroll
        for (int j = 0; j < 4; ++j) {
            const int slot = lbase[b[j]] + r[j];
            if (slot < BCAP)
                bpair[(b[j] << BSH) + slot] = (ss[j] << 8) | (dd[j] & 255);
        }
    }
}

// one WG per bucket: inline prefix over min(bcnt,BCAP) + LDS counting sort
__global__ void sortfill_kernel(const int* __restrict__ bpair,
                                const int* __restrict__ bcnt,
                                int* __restrict__ offset, int* __restrict__ csr) {
    __shared__ int red[256];
    __shared__ int hist[256];
    __shared__ int l[256];
    __shared__ int cursor[256];
    const int b = blockIdx.x;
    const int t = threadIdx.x;
    const int base = b << BSH;

    // prefix: cbase = sum_{i<b} min(bcnt[i],BCAP); cnt = min(bcnt[b],BCAP)
    int part = 0;
    for (int i = t; i < b; i += 256) {
        int c = bcnt[i];
        part += (c < BCAP ? c : BCAP);
    }
    red[t] = part;
    __syncthreads();
    for (int d = 128; d > 0; d >>= 1) {
        if (t < d) red[t] += red[t + d];
        __syncthreads();
    }
    const int cbase = red[0];
    int cnt = bcnt[b];
    cnt = cnt < BCAP ? cnt : BCAP;
    if (b == NBUCK - 1 && t == 0) offset[N_NODES] = cbase + cnt;
    __syncthreads();

    hist[t] = 0;
    __syncthreads();
    for (int i = t; i < cnt; i += 256)
        atomicAdd(&hist[bpair[base + i] & 255], 1);
    __syncthreads();

    const int v = hist[t];
    l[t] = v;
    __syncthreads();
    for (int d = 1; d < 256; d <<= 1) {
        int u = l[t];
        if (t >= d) u += l[t - d];
        __syncthreads();
        l[t] = u;
        __syncthreads();
    }
    const int gpos = cbase + l[t] - v;              // exclusive
    const int node = (b << 8) + t;
    if (node < N_NODES) offset[node] = gpos;
    cursor[t] = gpos;
    __syncthreads();

    for (int i = t; i < cnt; i += 256) {
        const int p = bpair[base + i];
        const int pos = atomicAdd(&cursor[p & 255], 1);
        csr[pos] = p >> 8;
    }
}

// ---------------------------------------------------------------------------
// Dual-stream gather macros: two independent 8-deep load pipelines per wave.
// ---------------------------------------------------------------------------
#define GATHER8(S, ACC)                                                        \
    {                                                                          \
        const int t0 = __shfl(S, j + 0), t1 = __shfl(S, j + 1);                \
        const int t2 = __shfl(S, j + 2), t3 = __shfl(S, j + 3);                \
        const int t4 = __shfl(S, j + 4), t5 = __shfl(S, j + 5);                \
        const int t6 = __shfl(S, j + 6), t7 = __shfl(S, j + 7);                \
        const float u0 = (float)x[t0 * 64 + f], u1 = (float)x[t1 * 64 + f];    \
        const float u2 = (float)x[t2 * 64 + f], u3 = (float)x[t3 * 64 + f];    \
        const float u4 = (float)x[t4 * 64 + f], u5 = (float)x[t5 * 64 + f];    \
        const float u6 = (float)x[t6 * 64 + f], u7 = (float)x[t7 * 64 + f];    \
        ACC += ((u0 + u1) + (u2 + u3)) + ((u4 + u5) + (u6 + u7));              \
    }
#define GATHER4(S, J, ACC)                                                     \
    {                                                                          \
        const int t0 = __shfl(S, J + 0), t1 = __shfl(S, J + 1);                \
        const int t2 = __shfl(S, J + 2), t3 = __shfl(S, J + 3);                \
        const float u0 = (float)x[t0 * 64 + f], u1 = (float)x[t1 * 64 + f];    \
        const float u2 = (float)x[t2 * 64 + f], u3 = (float)x[t3 * 64 + f];    \
        ACC += (u0 + u1) + (u2 + u3);                                          \
    }

// ---------------------------------------------------------------------------
// Fused gather + MLP: per block, 4 waves each gather 16 rows (self + neighbor
// sum) into hs[wv], then xout = bf16(relu(relu(hs @ wa + ba) @ wb + bb)).
// POOL=1 (layer 3): segmented mean-pool numerator into gsum atomics.
// ---------------------------------------------------------------------------
template <int POOL>
__global__ void gmlp_kernel(const bf16_t* __restrict__ x,
                            const int* __restrict__ offset,
                            const int* __restrict__ csr,
                            const float* __restrict__ wa, const float* __restrict__ ba,
                            const float* __restrict__ wb, const float* __restrict__ bb,
                            bf16_t* __restrict__ xout,
                            const int* __restrict__ batch,
                            float* __restrict__ gsum) {
    __shared__ __align__(16) bf16_t wfrag[2][8][64][8];  // [mat][ct*2+ks][lane][j]
    __shared__ __align__(16) bf16_t hs[4][16][72];       // per-wave, agg rows then h1/h2
    __shared__ float biasA[64], biasB[64];

    const int tid  = threadIdx.x;
    const int wv   = tid >> 6;
    const int lane = tid & 63;
    const int l15  = lane & 15;
    const int quad = lane >> 4;

    {
        const int k  = tid >> 2;
        const int n0 = (tid & 3) << 4;
        const int ks = k >> 5, qd = (k >> 3) & 3, jj = k & 7;
        const int fi = ((n0 >> 4) << 1) + ks;
#pragma unroll
        for (int m = 0; m < 2; ++m) {
            const float* w = m ? wb : wa;
            const f32x4 v0 = *(const f32x4*)(w + k * 64 + n0);
            const f32x4 v1 = *(const f32x4*)(w + k * 64 + n0 + 4);
            const f32x4 v2 = *(const f32x4*)(w + k * 64 + n0 + 8);
            const f32x4 v3 = *(const f32x4*)(w + k * 64 + n0 + 12);
#pragma unroll
            for (int l = 0; l < 4; ++l) {
                wfrag[m][fi][qd * 16 + l][jj]      = (bf16_t)v0[l];
                wfrag[m][fi][qd * 16 + 4 + l][jj]  = (bf16_t)v1[l];
                wfrag[m][fi][qd * 16 + 8 + l][jj]  = (bf16_t)v2[l];
                wfrag[m][fi][qd * 16 + 12 + l][jj] = (bf16_t)v3[l];
            }
        }
        if (tid < 64) biasA[tid] = ba[tid];
        else if (tid < 128) biasB[tid - 64] = bb[tid - 64];
    }
    __syncthreads();

    const int rb = blockIdx.x * 64 + wv * 16;
    const int f  = lane;

    // ---- gather 16 rows into hs[wv][r][lane] (dual pipeline: rows i and i+8) ----
    for (int i = 0; i < 8; ++i) {
        const int nA = rb + i;
        const int nB = rb + i + 8;
        const bool vA = nA < N_NODES;
        const bool vB = nB < N_NODES;
        const int oA = vA ? offset[nA] : 0;
        const int eA = vA ? offset[nA + 1] : 0;
        const int oB = vB ? offset[nB] : 0;
        const int eB = vB ? offset[nB + 1] : 0;
        const int dA = eA - oA, dB = eB - oB;

        float accA = vA ? (float)x[nA * 64 + f] : 0.f;
        float accB = vB ? (float)x[nB * 64 + f] : 0.f;

        for (int base = 0; base < dA || base < dB; base += 64) {
            const int ra = dA - base, rb2 = dB - base;
            const int cntA = ra <= 0 ? 0 : (ra < 64 ? ra : 64);
            const int cntB = rb2 <= 0 ? 0 : (rb2 < 64 ? rb2 : 64);
            int sA = 0, sB = 0;
            if (f < cntA) sA = csr[oA + base + f];
            if (f < cntB) sB = csr[oB + base + f];

            int j = 0;
            for (; j + 8 <= cntA && j + 8 <= cntB; j += 8) {
                GATHER8(sA, accA)
                GATHER8(sB, accB)
            }
            int jA = j, jB = j;
            for (; jA + 8 <= cntA; jA += 8) { const int j = jA; GATHER8(sA, accA) }
            for (; jB + 8 <= cntB; jB += 8) { const int j = jB; GATHER8(sB, accB) }
            if (jA + 4 <= cntA && jB + 4 <= cntB) {
                GATHER4(sA, jA, accA)
                GATHER4(sB, jB, accB)
                jA += 4; jB += 4;
            }
            if (jA + 4 <= cntA) { GATHER4(sA, jA, accA) jA += 4; }
            if (jB + 4 <= cntB) { GATHER4(sB, jB, accB) jB += 4; }
            for (; jA < cntA; ++jA) { const int t = __shfl(sA, jA); accA += (float)x[t * 64 + f]; }
            for (; jB < cntB; ++jB) { const int t = __shfl(sB, jB); accB += (float)x[t * 64 + f]; }
        }
        hs[wv][i][lane]     = (bf16_t)accA;
        hs[wv][i + 8][lane] = (bf16_t)accB;
    }

    // ---- A-frags from gathered rows (per-wave LDS, no block sync needed) ----
    bf16x8 af[2];
#pragma unroll
    for (int ks = 0; ks < 2; ++ks)
        af[ks] = *(const bf16x8*)(&hs[wv][l15][ks * 32 + quad * 8]);

    // GEMM1 -> relu -> hs
#pragma unroll
    for (int ct = 0; ct < 4; ++ct) {
        const bf16x8 b0 = *(const bf16x8*)&wfrag[0][ct * 2 + 0][lane][0];
        const bf16x8 b1 = *(const bf16x8*)&wfrag[0][ct * 2 + 1][lane][0];
        f32x4 acc = {0.f, 0.f, 0.f, 0.f};
        acc = __builtin_amdgcn_mfma_f32_16x16x32_bf16(af[0], b0, acc, 0, 0, 0);
        acc = __builtin_amdgcn_mfma_f32_16x16x32_bf16(af[1], b1, acc, 0, 0, 0);
        const float bv = biasA[ct * 16 + l15];
#pragma unroll
        for (int r = 0; r < 4; ++r) {
            float h = acc[r] + bv;
            h = h > 0.f ? h : 0.f;
            hs[wv][quad * 4 + r][ct * 16 + l15] = (bf16_t)h;
        }
    }

    bf16x8 a2[2];
#pragma unroll
    for (int ks = 0; ks < 2; ++ks)
        a2[ks] = *(const bf16x8*)(&hs[wv][l15][ks * 32 + quad * 8]);

    // GEMM2 -> relu -> hs
#pragma unroll
    for (int ct = 0; ct < 4; ++ct) {
        const bf16x8 b0 = *(const bf16x8*)&wfrag[1][ct * 2 + 0][lane][0];
        const bf16x8 b1 = *(const bf16x8*)&wfrag[1][ct * 2 + 1][lane][0];
        f32x4 acc = {0.f, 0.f, 0.f, 0.f};
        acc = __builtin_amdgcn_mfma_f32_16x16x32_bf16(a2[0], b0, acc, 0, 0, 0);
        acc = __builtin_amdgcn_mfma_f32_16x16x32_bf16(a2[1], b1, acc, 0, 0, 0);
        const float bv = biasB[ct * 16 + l15];
#pragma unroll
        for (int r = 0; r < 4; ++r) {
            float h = acc[r] + bv;
            h = h > 0.f ? h : 0.f;
            hs[wv][quad * 4 + r][ct * 16 + l15] = (bf16_t)h;
        }
    }

    if (POOL) {
        // segmented mean-pool numerator: ~1 atomic per graph run per wave
        int cur = -1;
        float acc = 0.f;
        for (int r = 0; r < 16; ++r) {
            const int row = rb + r;
            if (row >= N_NODES) break;
            const int g = batch[row];           // wave-uniform
            const float v = (float)hs[wv][r][lane];
            if (g != cur) {
                if (cur >= 0) unsafeAtomicAdd(gsum + cur * 64 + lane, acc);
                acc = 0.f;
                cur = g;
            }
            acc += v;
        }
        if (cur >= 0) unsafeAtomicAdd(gsum + cur * 64 + lane, acc);
    } else {
        const int colg = (lane & 7) * 8;
#pragma unroll
        for (int sx = 0; sx < 2; ++sx) {
            const int r16 = (lane >> 3) + 8 * sx;
            const int grow = rb + r16;
            const bf16x8 v = *(const bf16x8*)&hs[wv][r16][colg];
            if (grow < N_NODES)
                *(bf16x8*)(xout + grow * 64 + colg) = v;
        }
    }
}

// out[g][c] = (gsum[g]/max(cnt,1)) . wc[:,c] + bc[c]; cnt via binary search
__global__ void cls_kernel(const float* __restrict__ gsum,
                           const int* __restrict__ batch,
                           const float* __restrict__ wc, const float* __restrict__ bc,
                           float* __restrict__ out) {
    const int g = blockIdx.x;
    const int c = threadIdx.x;
    if (c >= N_CLS) return;
    int lo = 0, hi = N_NODES;
    while (lo < hi) { const int m = (lo + hi) >> 1; if (batch[m] < g) lo = m + 1; else hi = m; }
    const int lb = lo;
    lo = 0; hi = N_NODES;
    while (lo < hi) { const int m = (lo + hi) >> 1; if (batch[m] <= g) lo = m + 1; else hi = m; }
    const int cnt = lo - lb;
    const float inv = 1.f / (float)(cnt > 1 ? cnt : 1);
    float acc = bc[c];
    for (int k = 0; k < 64; ++k)
        acc += gsum[g * 64 + k] * inv * wc[k * N_CLS + c];
    out[g * N_CLS + c] = acc;
}

// ---------------------------------------------------------------------------
extern "C" void kernel_launch(void* const* d_in, const int* in_sizes, int n_in,
                              void* d_out, int out_size, void* d_ws, size_t ws_size,
                              hipStream_t stream) {
    const float* x   = (const float*)d_in[0];
    const float* w1a = (const float*)d_in[1];
    const float* b1a = (const float*)d_in[2];
    const float* w1b = (const float*)d_in[3];
    const float* b1b = (const float*)d_in[4];
    const float* w2a = (const float*)d_in[5];
    const float* b2a = (const float*)d_in[6];
    const float* w2b = (const float*)d_in[7];
    const float* b2b = (const float*)d_in[8];
    const float* w3a = (const float*)d_in[9];
    const float* b3a = (const float*)d_in[10];
    const float* w3b = (const float*)d_in[11];
    const float* b3b = (const float*)d_in[12];
    const float* wc  = (const float*)d_in[13];
    const float* bc  = (const float*)d_in[14];
    const int*   ei    = (const int*)d_in[15];
    const int*   batch = (const int*)d_in[16];
    float* out = (float*)d_out;

    // workspace layout (~50.1 MB, 16B-aligned)
    char*   ws     = (char*)d_ws;
    int*    bcnt   = (int*)ws;                      // 391 ints (pad 1568)
    int*    offset = (int*)(ws + 3136);             // N+1 ints (pad 400016)
    int*    csr    = (int*)(ws + 403152);           // E ints = 4,800,000
    int*    bpair  = (int*)(ws + 5203152);          // 391*4096*4 = 6,406,144
    bf16_t* xbf    = (bf16_t*)(ws + 11609296);      // 12,800,000
    bf16_t* h      = (bf16_t*)(ws + 24409296);      // 12,800,000
    bf16_t* xA     = (bf16_t*)(ws + 37209296);      // 12,800,000
    float*  gsum   = (float*)(ws + 50009296);       // 32,768

    const int e4grid = (N_EDGES / 4 + 255) / 256;   // 1172
    const int tiles  = (N_NODES + 63) / 64;         // 1563

    // x -> bf16 (+ zero bcnt/gsum)
    tobf_kernel<<<(N_NODES * 64) / (256 * 8), 256, 0, stream>>>(x, xbf, bcnt, gsum);

    // CSR build (once, reused 3x)
    binA_kernel<<<e4grid, 256, 0, stream>>>(ei, bcnt, bpair);
    sortfill_kernel<<<NBUCK, 256, 0, stream>>>(bpair, bcnt, offset, csr);

    // fused gather+MLP layers (ping-pong buffers: xbf -> xA -> h -> pool)
    gmlp_kernel<0><<<tiles, 256, 0, stream>>>(xbf, offset, csr, w1a, b1a, w1b, b1b, xA, nullptr, nullptr);
    gmlp_kernel<0><<<tiles, 256, 0, stream>>>(xA, offset, csr, w2a, b2a, w2b, b2b, h, nullptr, nullptr);
    gmlp_kernel<1><<<tiles, 256, 0, stream>>>(h, offset, csr, w3a, b3a, w3b, b3b, nullptr, batch, gsum);

    // classify
    cls_kernel<<<N_GRAPH, 64, 0, stream>>>(gsum, batch, wc, bc, out);
}

// Round 2
// 343.219 us; speedup vs baseline: 1.0957x; 1.0957x over previous
//
#include <hip/hip_runtime.h>
#include <hip/hip_bf16.h>

// GIN: 3x fused [CSR gather-sum + MLP(64->64->64) + relu] + mean-pool(128) + linear(64->10)
// gmlp v2: 512-thread blocks (8 waves), 64 rows/block. Each wave gathers 8 rows
//   (dual 8-deep load pipelines, 4 iterations); wave PAIRS share a 16-row MFMA tile
//   (each wave does 2 of 4 col-tiles). Offsets prefetched via lane-load + shfl.
//   LDS 35.3KB -> 4 blocks/CU = 32 waves/CU (wave-capped), grid 1563 -> refill.
// CSR: 391-bucket binning + per-bucket counting sort w/ inline prefix.
// tobf zeroes bcnt+gsum. 7 dispatches total.

#define N_NODES 100000
#define N_EDGES 1200000
#define N_GRAPH 128
#define N_CLS   10
#define NBUCK   391        // dst >> 8
#define BCAP    4096       // per-bucket capacity (mean 3070, +18 sigma)
#define BSH     12         // log2(BCAP)

typedef __bf16 bf16_t;
typedef __bf16 bf16x8 __attribute__((ext_vector_type(8)));
typedef float  f32x4  __attribute__((ext_vector_type(4)));

// ---------------- x -> bf16 (+ zero bcnt/gsum for later kernels) ----------------
__global__ void tobf_kernel(const float* __restrict__ x, bf16_t* __restrict__ xb,
                            int* __restrict__ bcnt, float* __restrict__ gsum) {
    if (blockIdx.x == 0) {
        for (int i = threadIdx.x; i < NBUCK; i += 256) bcnt[i] = 0;
    } else if (blockIdx.x == 1) {
        f32x4* g4 = (f32x4*)gsum;
        for (int i = threadIdx.x; i < N_GRAPH * 16; i += 256)   // 8192 f32
            g4[i] = (f32x4){0.f, 0.f, 0.f, 0.f};
    }
    const int i = (blockIdx.x * 256 + threadIdx.x) * 8;
    const f32x4 a = *(const f32x4*)(x + i);
    const f32x4 b = *(const f32x4*)(x + i + 4);
    bf16x8 o;
#pragma unroll
    for (int j = 0; j < 4; ++j) { o[j] = (bf16_t)a[j]; o[4 + j] = (bf16_t)b[j]; }
    *(bf16x8*)(xb + i) = o;
}

// ---------------- CSR build ----------------
__global__ void binA_kernel(const int* __restrict__ ei,
                            int* __restrict__ bcnt,
                            int* __restrict__ bpair) {
    __shared__ int lcnt[NBUCK];
    __shared__ int lbase[NBUCK];
    const int t = threadIdx.x;
    for (int b = t; b < NBUCK; b += 256) lcnt[b] = 0;
    __syncthreads();
    const int e0 = (blockIdx.x * 256 + t) * 4;
    int4 s4, d4; int b[4], r[4];
    const bool valid = e0 < N_EDGES;               // N_EDGES % 4 == 0
    if (valid) {
        s4 = *(const int4*)(ei + e0);
        d4 = *(const int4*)(ei + N_EDGES + e0);
        b[0] = d4.x >> 8; b[1] = d4.y >> 8; b[2] = d4.z >> 8; b[3] = d4.w >> 8;
        r[0] = atomicAdd(&lcnt[b[0]], 1);
        r[1] = atomicAdd(&lcnt[b[1]], 1);
        r[2] = atomicAdd(&lcnt[b[2]], 1);
        r[3] = atomicAdd(&lcnt[b[3]], 1);
    }
    __syncthreads();
    for (int bb = t; bb < NBUCK; bb += 256) {
        const int c = lcnt[bb];
        lbase[bb] = c ? atomicAdd(&bcnt[bb], c) : 0;
    }
    __syncthreads();
    if (valid) {
        const int ss[4] = {s4.x, s4.y, s4.z, s4.w};
        const int dd[4] = {d4.x, d4.y, d4.z, d4.w};
#pragma unroll
        for (int j = 0; j < 4; ++j) {
            const int slot = lbase[b[j]] + r[j];
            if (slot < BCAP)
                bpair[(b[j] << BSH) + slot] = (ss[j] << 8) | (dd[j] & 255);
        }
    }
}

// one WG per bucket: inline prefix over min(bcnt,BCAP) + LDS counting sort
__global__ void sortfill_kernel(const int* __restrict__ bpair,
                                const int* __restrict__ bcnt,
                                int* __restrict__ offset, int* __restrict__ csr) {
    __shared__ int red[256];
    __shared__ int hist[256];
    __shared__ int l[256];
    __shared__ int cursor[256];
    const int b = blockIdx.x;
    const int t = threadIdx.x;
    const int base = b << BSH;

    // prefix: cbase = sum_{i<b} min(bcnt[i],BCAP); cnt = min(bcnt[b],BCAP)
    int part = 0;
    for (int i = t; i < b; i += 256) {
        int c = bcnt[i];
        part += (c < BCAP ? c : BCAP);
    }
    red[t] = part;
    __syncthreads();
    for (int d = 128; d > 0; d >>= 1) {
        if (t < d) red[t] += red[t + d];
        __syncthreads();
    }
    const int cbase = red[0];
    int cnt = bcnt[b];
    cnt = cnt < BCAP ? cnt : BCAP;
    if (b == NBUCK - 1 && t == 0) offset[N_NODES] = cbase + cnt;
    __syncthreads();

    hist[t] = 0;
    __syncthreads();
    for (int i = t; i < cnt; i += 256)
        atomicAdd(&hist[bpair[base + i] & 255], 1);
    __syncthreads();

    const int v = hist[t];
    l[t] = v;
    __syncthreads();
    for (int d = 1; d < 256; d <<= 1) {
        int u = l[t];
        if (t >= d) u += l[t - d];
        __syncthreads();
        l[t] = u;
        __syncthreads();
    }
    const int gpos = cbase + l[t] - v;              // exclusive
    const int node = (b << 8) + t;
    if (node < N_NODES) offset[node] = gpos;
    cursor[t] = gpos;
    __syncthreads();

    for (int i = t; i < cnt; i += 256) {
        const int p = bpair[base + i];
        const int pos = atomicAdd(&cursor[p & 255], 1);
        csr[pos] = p >> 8;
    }
}

// ---------------------------------------------------------------------------
// Dual-stream gather macros: two independent 8-deep load pipelines per wave.
// ---------------------------------------------------------------------------
#define GATHER8(S, ACC)                                                        \
    {                                                                          \
        const int t0 = __shfl(S, j + 0), t1 = __shfl(S, j + 1);                \
        const int t2 = __shfl(S, j + 2), t3 = __shfl(S, j + 3);                \
        const int t4 = __shfl(S, j + 4), t5 = __shfl(S, j + 5);                \
        const int t6 = __shfl(S, j + 6), t7 = __shfl(S, j + 7);                \
        const float u0 = (float)x[t0 * 64 + f], u1 = (float)x[t1 * 64 + f];    \
        const float u2 = (float)x[t2 * 64 + f], u3 = (float)x[t3 * 64 + f];    \
        const float u4 = (float)x[t4 * 64 + f], u5 = (float)x[t5 * 64 + f];    \
        const float u6 = (float)x[t6 * 64 + f], u7 = (float)x[t7 * 64 + f];    \
        ACC += ((u0 + u1) + (u2 + u3)) + ((u4 + u5) + (u6 + u7));              \
    }
#define GATHER4(S, J, ACC)                                                     \
    {                                                                          \
        const int t0 = __shfl(S, J + 0), t1 = __shfl(S, J + 1);                \
        const int t2 = __shfl(S, J + 2), t3 = __shfl(S, J + 3);                \
        const float u0 = (float)x[t0 * 64 + f], u1 = (float)x[t1 * 64 + f];    \
        const float u2 = (float)x[t2 * 64 + f], u3 = (float)x[t3 * 64 + f];    \
        ACC += (u0 + u1) + (u2 + u3);                                          \
    }

// ---------------------------------------------------------------------------
// Fused gather + MLP, wave-paired.
// Block = 512 threads = 8 waves = 4 pairs; block covers 64 rows (4 x 16-row tiles).
// Wave w: pair p=w>>1, half=w&1. Gathers 8 rows (local rows half*8 .. half*8+7)
// into hs[p]; pair computes 16x64 MLP, each wave owning 2 of 4 col-tiles.
// POOL=1 (layer 3): half==0 wave does segmented mean-pool numerator atomics.
// ---------------------------------------------------------------------------
template <int POOL>
__global__ void gmlp_kernel(const bf16_t* __restrict__ x,
                            const int* __restrict__ offset,
                            const int* __restrict__ csr,
                            const float* __restrict__ wa, const float* __restrict__ ba,
                            const float* __restrict__ wb, const float* __restrict__ bb,
                            bf16_t* __restrict__ xout,
                            const int* __restrict__ batch,
                            float* __restrict__ gsum) {
    __shared__ __align__(16) bf16_t wfrag[2][8][64][8];  // [mat][ct*2+ks][lane][j]
    __shared__ __align__(16) bf16_t hs[4][16][72];       // per-pair: agg rows, then h2
    __shared__ __align__(16) bf16_t h2[4][16][72];       // per-pair: h1 (GEMM1 out)
    __shared__ float biasA[64], biasB[64];

    const int tid  = threadIdx.x;
    const int wv   = tid >> 6;          // 0..7
    const int p    = wv >> 1;           // pair 0..3
    const int half = wv & 1;
    const int lane = tid & 63;
    const int l15  = lane & 15;
    const int quad = lane >> 4;

    if (tid < 256) {
        const int k  = tid >> 2;
        const int n0 = (tid & 3) << 4;
        const int ks = k >> 5, qd = (k >> 3) & 3, jj = k & 7;
        const int fi = ((n0 >> 4) << 1) + ks;
#pragma unroll
        for (int m = 0; m < 2; ++m) {
            const float* w = m ? wb : wa;
            const f32x4 v0 = *(const f32x4*)(w + k * 64 + n0);
            const f32x4 v1 = *(const f32x4*)(w + k * 64 + n0 + 4);
            const f32x4 v2 = *(const f32x4*)(w + k * 64 + n0 + 8);
            const f32x4 v3 = *(const f32x4*)(w + k * 64 + n0 + 12);
#pragma unroll
            for (int l = 0; l < 4; ++l) {
                wfrag[m][fi][qd * 16 + l][jj]      = (bf16_t)v0[l];
                wfrag[m][fi][qd * 16 + 4 + l][jj]  = (bf16_t)v1[l];
                wfrag[m][fi][qd * 16 + 8 + l][jj]  = (bf16_t)v2[l];
                wfrag[m][fi][qd * 16 + 12 + l][jj] = (bf16_t)v3[l];
            }
        }
        if (tid < 64) biasA[tid] = ba[tid];
        else if (tid < 128) biasB[tid - 64] = bb[tid - 64];
    }
    // no sync here: the sync after the gather phase makes wfrag/bias visible.

    const int rbp = blockIdx.x * 64 + p * 16;   // pair's first row
    const int r0w = rbp + half * 8;             // this wave's first row
    const int f   = lane;

    // prefetch the 9 offsets this wave needs (rows r0w..r0w+8), broadcast via shfl
    int offv = 0;
    {
        int rr = r0w + lane;
        rr = rr < N_NODES ? rr : N_NODES;
        if (lane < 9) offv = offset[rr];
    }

    // ---- gather 8 rows into hs[p] (dual pipeline: local rows half*8+i, +4) ----
    for (int i = 0; i < 4; ++i) {
        const int nA = r0w + i;
        const int nB = r0w + i + 4;
        const bool vA = nA < N_NODES;
        const bool vB = nB < N_NODES;
        const int oA = __shfl(offv, i),     eA = __shfl(offv, i + 1);
        const int oB = __shfl(offv, i + 4), eB = __shfl(offv, i + 5);
        const int dA = eA - oA, dB = eB - oB;

        float accA = vA ? (float)x[nA * 64 + f] : 0.f;
        float accB = vB ? (float)x[nB * 64 + f] : 0.f;

        for (int base = 0; base < dA || base < dB; base += 64) {
            const int ra = dA - base, rb2 = dB - base;
            const int cntA = ra <= 0 ? 0 : (ra < 64 ? ra : 64);
            const int cntB = rb2 <= 0 ? 0 : (rb2 < 64 ? rb2 : 64);
            int sA = 0, sB = 0;
            if (f < cntA) sA = csr[oA + base + f];
            if (f < cntB) sB = csr[oB + base + f];

            int j = 0;
            for (; j + 8 <= cntA && j + 8 <= cntB; j += 8) {
                GATHER8(sA, accA)
                GATHER8(sB, accB)
            }
            int jA = j, jB = j;
            for (; jA + 8 <= cntA; jA += 8) { const int j = jA; GATHER8(sA, accA) }
            for (; jB + 8 <= cntB; jB += 8) { const int j = jB; GATHER8(sB, accB) }
            if (jA + 4 <= cntA && jB + 4 <= cntB) {
                GATHER4(sA, jA, accA)
                GATHER4(sB, jB, accB)
                jA += 4; jB += 4;
            }
            if (jA + 4 <= cntA) { GATHER4(sA, jA, accA) jA += 4; }
            if (jB + 4 <= cntB) { GATHER4(sB, jB, accB) jB += 4; }
            for (; jA < cntA; ++jA) { const int t = __shfl(sA, jA); accA += (float)x[t * 64 + f]; }
            for (; jB < cntB; ++jB) { const int t = __shfl(sB, jB); accB += (float)x[t * 64 + f]; }
        }
        hs[p][half * 8 + i][lane]     = (bf16_t)accA;
        hs[p][half * 8 + i + 4][lane] = (bf16_t)accB;
    }

    __syncthreads();   // gather done + weights visible

    // ---- GEMM1: read hs[p], write relu -> h2[p]; this wave owns ct = half*2 + {0,1}
    {
        bf16x8 af[2];
#pragma unroll
        for (int ks = 0; ks < 2; ++ks)
            af[ks] = *(const bf16x8*)(&hs[p][l15][ks * 32 + quad * 8]);
#pragma unroll
        for (int c = 0; c < 2; ++c) {
            const int ct = half * 2 + c;
            const bf16x8 b0 = *(const bf16x8*)&wfrag[0][ct * 2 + 0][lane][0];
            const bf16x8 b1 = *(const bf16x8*)&wfrag[0][ct * 2 + 1][lane][0];
            f32x4 acc = {0.f, 0.f, 0.f, 0.f};
            acc = __builtin_amdgcn_mfma_f32_16x16x32_bf16(af[0], b0, acc, 0, 0, 0);
            acc = __builtin_amdgcn_mfma_f32_16x16x32_bf16(af[1], b1, acc, 0, 0, 0);
            const float bv = biasA[ct * 16 + l15];
#pragma unroll
            for (int r = 0; r < 4; ++r) {
                float h = acc[r] + bv;
                h = h > 0.f ? h : 0.f;
                h2[p][quad * 4 + r][ct * 16 + l15] = (bf16_t)h;
            }
        }
    }

    __syncthreads();   // h1 complete

    // ---- GEMM2: read h2[p], write relu -> hs[p]
    {
        bf16x8 a2[2];
#pragma unroll
        for (int ks = 0; ks < 2; ++ks)
            a2[ks] = *(const bf16x8*)(&h2[p][l15][ks * 32 + quad * 8]);
#pragma unroll
        for (int c = 0; c < 2; ++c) {
            const int ct = half * 2 + c;
            const bf16x8 b0 = *(const bf16x8*)&wfrag[1][ct * 2 + 0][lane][0];
            const bf16x8 b1 = *(const bf16x8*)&wfrag[1][ct * 2 + 1][lane][0];
            f32x4 acc = {0.f, 0.f, 0.f, 0.f};
            acc = __builtin_amdgcn_mfma_f32_16x16x32_bf16(a2[0], b0, acc, 0, 0, 0);
            acc = __builtin_amdgcn_mfma_f32_16x16x32_bf16(a2[1], b1, acc, 0, 0, 0);
            const float bv = biasB[ct * 16 + l15];
#pragma unroll
            for (int r = 0; r < 4; ++r) {
                float h = acc[r] + bv;
                h = h > 0.f ? h : 0.f;
                hs[p][quad * 4 + r][ct * 16 + l15] = (bf16_t)h;
            }
        }
    }

    __syncthreads();   // h2 (final) complete

    if (POOL) {
        // segmented mean-pool numerator: one wave per pair scans its 16 rows
        if (half == 0) {
            int cur = -1;
            float acc = 0.f;
            for (int r = 0; r < 16; ++r) {
                const int row = rbp + r;
                if (row >= N_NODES) break;
                const int g = batch[row];           // wave-uniform
                const float v = (float)hs[p][r][lane];
                if (g != cur) {
                    if (cur >= 0) unsafeAtomicAdd(gsum + cur * 64 + lane, acc);
                    acc = 0.f;
                    cur = g;
                }
                acc += v;
            }
            if (cur >= 0) unsafeAtomicAdd(gsum + cur * 64 + lane, acc);
        }
    } else {
        // wave stores its 8 rows: one bf16x8 per lane
        const int row16 = half * 8 + (lane >> 3);
        const int colg  = (lane & 7) * 8;
        const int grow  = rbp + row16;
        const bf16x8 v = *(const bf16x8*)&hs[p][row16][colg];
        if (grow < N_NODES)
            *(bf16x8*)(xout + grow * 64 + colg) = v;
    }
}

// out[g][c] = (gsum[g]/max(cnt,1)) . wc[:,c] + bc[c]; cnt via binary search
__global__ void cls_kernel(const float* __restrict__ gsum,
                           const int* __restrict__ batch,
                           const float* __restrict__ wc, const float* __restrict__ bc,
                           float* __restrict__ out) {
    const int g = blockIdx.x;
    const int c = threadIdx.x;
    if (c >= N_CLS) return;
    int lo = 0, hi = N_NODES;
    while (lo < hi) { const int m = (lo + hi) >> 1; if (batch[m] < g) lo = m + 1; else hi = m; }
    const int lb = lo;
    lo = 0; hi = N_NODES;
    while (lo < hi) { const int m = (lo + hi) >> 1; if (batch[m] <= g) lo = m + 1; else hi = m; }
    const int cnt = lo - lb;
    const float inv = 1.f / (float)(cnt > 1 ? cnt : 1);
    float acc = bc[c];
    for (int k = 0; k < 64; ++k)
        acc += gsum[g * 64 + k] * inv * wc[k * N_CLS + c];
    out[g * N_CLS + c] = acc;
}

// ---------------------------------------------------------------------------
extern "C" void kernel_launch(void* const* d_in, const int* in_sizes, int n_in,
                              void* d_out, int out_size, void* d_ws, size_t ws_size,
                              hipStream_t stream) {
    const float* x   = (const float*)d_in[0];
    const float* w1a = (const float*)d_in[1];
    const float* b1a = (const float*)d_in[2];
    const float* w1b = (const float*)d_in[3];
    const float* b1b = (const float*)d_in[4];
    const float* w2a = (const float*)d_in[5];
    const float* b2a = (const float*)d_in[6];
    const float* w2b = (const float*)d_in[7];
    const float* b2b = (const float*)d_in[8];
    const float* w3a = (const float*)d_in[9];
    const float* b3a = (const float*)d_in[10];
    const float* w3b = (const float*)d_in[11];
    const float* b3b = (const float*)d_in[12];
    const float* wc  = (const float*)d_in[13];
    const float* bc  = (const float*)d_in[14];
    const int*   ei    = (const int*)d_in[15];
    const int*   batch = (const int*)d_in[16];
    float* out = (float*)d_out;

    // workspace layout (~50.1 MB, 16B-aligned)
    char*   ws     = (char*)d_ws;
    int*    bcnt   = (int*)ws;                      // 391 ints (pad 1568)
    int*    offset = (int*)(ws + 3136);             // N+1 ints (pad 400016)
    int*    csr    = (int*)(ws + 403152);           // E ints = 4,800,000
    int*    bpair  = (int*)(ws + 5203152);          // 391*4096*4 = 6,406,144
    bf16_t* xbf    = (bf16_t*)(ws + 11609296);      // 12,800,000
    bf16_t* h      = (bf16_t*)(ws + 24409296);      // 12,800,000
    bf16_t* xA     = (bf16_t*)(ws + 37209296);      // 12,800,000
    float*  gsum   = (float*)(ws + 50009296);       // 32,768

    const int e4grid = (N_EDGES / 4 + 255) / 256;   // 1172
    const int tiles  = (N_NODES + 63) / 64;         // 1563

    // x -> bf16 (+ zero bcnt/gsum)
    tobf_kernel<<<(N_NODES * 64) / (256 * 8), 256, 0, stream>>>(x, xbf, bcnt, gsum);

    // CSR build (once, reused 3x)
    binA_kernel<<<e4grid, 256, 0, stream>>>(ei, bcnt, bpair);
    sortfill_kernel<<<NBUCK, 256, 0, stream>>>(bpair, bcnt, offset, csr);

    // fused gather+MLP layers (ping-pong buffers: xbf -> xA -> h -> pool)
    gmlp_kernel<0><<<tiles, 512, 0, stream>>>(xbf, offset, csr, w1a, b1a, w1b, b1b, xA, nullptr, nullptr);
    gmlp_kernel<0><<<tiles, 512, 0, stream>>>(xA, offset, csr, w2a, b2a, w2b, b2b, h, nullptr, nullptr);
    gmlp_kernel<1><<<tiles, 512, 0, stream>>>(h, offset, csr, w3a, b3a, w3b, b3b, nullptr, batch, gsum);

    // classify
    cls_kernel<<<N_GRAPH, 64, 0, stream>>>(gsum, batch, wc, bc, out);
}